// Round 10
// baseline (554.242 us; speedup 1.0000x reference)
//
#include <hip/hip_runtime.h>

#define BB 128
#define DD 8732
#define OO 16
#define CC 21
#define CH 16        // chunks per image in match phase A
#define CHUNK 546    // ceil(DD/CH)
#define NBLK_D 35    // ceil(DD/256)
#define NLB (BB * NBLK_D)
#define NV 35        // per-thread register values in topk

typedef __attribute__((address_space(3))) unsigned int lds_u32;
typedef const __attribute__((address_space(1))) unsigned int glb_u32;

__device__ __forceinline__ float smoothl1(float d) {
    float ad = fabsf(d);
    return (ad < 1.0f) ? 0.5f * d * d : ad - 0.5f;
}

// ---- Phase A: per-chunk argmax_d(iou) per gt o  +  per-d best over o ------
// key = (iou_bits << 32) | (DD-1-d)  -> u64 max == max iou, tie -> smallest d
__global__ __launch_bounds__(256) void match_a(
    const float4* __restrict__ gt_boxes,   // [B*O] xyxy
    const float4* __restrict__ db,         // [D] cxcywh
    unsigned long long* __restrict__ partial, // [B][O][CH]
    float* __restrict__ bovl,              // [B*D] best-over-o iou
    unsigned char* __restrict__ bidx,      // [B*D] argmax-over-o (first occurrence)
    int* __restrict__ counters)            // [BB+1]: per-image + global; zeroed here
{
    const int b = blockIdx.y, ch = blockIdx.x, tid = threadIdx.x;
    if (b == 0 && ch == 0) {
        for (int i = tid; i < BB + 1; i += 256) counters[i] = 0;
    }

    __shared__ float s_ax1[OO], s_ay1[OO], s_ax2[OO], s_ay2[OO], s_area[OO];
    __shared__ unsigned long long s_keys[OO][257];   // padded stride

    if (tid < OO) {
        float4 g = gt_boxes[b * OO + tid];
        s_ax1[tid] = g.x; s_ay1[tid] = g.y; s_ax2[tid] = g.z; s_ay2[tid] = g.w;
        s_area[tid] = (g.z - g.x) * (g.w - g.y);
    }
    __syncthreads();

    unsigned long long key[OO];
    #pragma unroll
    for (int o = 0; o < OO; ++o) key[o] = 0ull;

    const int d0 = ch * CHUNK;
    const int dend = min(d0 + CHUNK, DD);
    for (int d = d0 + tid; d < dend; d += 256) {
        float4 p = db[d];
        float px1 = p.x - p.z * 0.5f, py1 = p.y - p.w * 0.5f;
        float px2 = p.x + p.z * 0.5f, py2 = p.y + p.w * 0.5f;
        float area_b = (px2 - px1) * (py2 - py1);
        unsigned dl = (unsigned)(DD - 1 - d);
        float best = -1.0f; int bi = 0;
        #pragma unroll
        for (int o = 0; o < OO; ++o) {
            float w = fmaxf(fminf(s_ax2[o], px2) - fmaxf(s_ax1[o], px1), 0.0f);
            float h = fmaxf(fminf(s_ay2[o], py2) - fmaxf(s_ay1[o], py1), 0.0f);
            float inter = w * h;
            float iou = inter / (s_area[o] + area_b - inter);
            unsigned long long kk = ((unsigned long long)__float_as_uint(iou) << 32) | dl;
            if (kk > key[o]) key[o] = kk;
            if (iou > best) { best = iou; bi = o; }   // first occurrence over o
        }
        bovl[(size_t)b * DD + d] = best;
        bidx[(size_t)b * DD + d] = (unsigned char)bi;
    }
    #pragma unroll
    for (int o = 0; o < OO; ++o) s_keys[o][tid] = key[o];
    __syncthreads();

    const int o = tid >> 4, j = tid & 15;
    unsigned long long mx = s_keys[o][j];
    #pragma unroll
    for (int m = 1; m < 16; ++m) {
        unsigned long long v = s_keys[o][j + 16 * m];
        if (v > mx) mx = v;
    }
    #pragma unroll
    for (int off = 8; off; off >>= 1) {
        unsigned long long v = __shfl_xor(mx, off, 16);
        if (v > mx) mx = v;
    }
    if (j == 0) partial[((size_t)b * OO + o) * CH + ch] = mx;
}

// ---- mega kernel: fused CE/label/SL1 + per-image topk + global finalize ---
__global__ __launch_bounds__(256) void mega(
    const float4* __restrict__ loc_pred,
    const float*  __restrict__ cls,
    const float4* __restrict__ gt_boxes,
    const int*    __restrict__ gt_labels,
    const float4* __restrict__ db,
    const unsigned long long* __restrict__ partial,
    const float* __restrict__ bovl,
    const unsigned char* __restrict__ bidx,
    float* __restrict__ ce_neg,            // [B*D]
    float* __restrict__ part_sl1,          // [NLB] layout [b][jb]
    int*   __restrict__ part_np,
    float* __restrict__ part_ce,
    float* __restrict__ img_sl1,           // [BB]
    float* __restrict__ img_ce,            // [BB]
    int*   __restrict__ img_np,            // [BB]
    float* __restrict__ conf_neg_part,     // [BB]
    int*   __restrict__ counters,          // [BB+1]
    float* __restrict__ out)
{
    const int b = blockIdx.y, jb = blockIdx.x, tid = threadIdx.x;
    const int d = jb * 256 + tid;
    __shared__ float s_cls[256 * CC];      // 21504 B; aliased as hist in phase B
    __shared__ float s_ax1[OO], s_ay1[OO], s_ax2[OO], s_ay2[OO];
    __shared__ int   s_lab[OO], s_bdi[OO];
    __shared__ float s_f[12];
    __shared__ int   s_i[4];
    __shared__ unsigned s_pk[2];
    __shared__ int   s_last, s_glast;

    // ---- issue async global->LDS staging FIRST
    const int nrow = min(256, DD - jb * 256);
    const int nvec = nrow * CC / 4;
    const float4* src = (const float4*)(cls + ((size_t)b * DD + (size_t)jb * 256) * CC);
    if (nvec == 1344) {
        #pragma unroll
        for (int c = 0; c < 5; ++c) {
            int v = c * 256 + tid;
            __builtin_amdgcn_global_load_lds((glb_u32*)(src + v),
                                             (lds_u32*)&s_cls[v * 4], 16, 0, 0);
        }
        if (tid < 64) {
            int v = 5 * 256 + tid;
            __builtin_amdgcn_global_load_lds((glb_u32*)(src + v),
                                             (lds_u32*)&s_cls[v * 4], 16, 0, 0);
        }
    } else {
        for (int v = tid; v < nvec; v += 256)
            __builtin_amdgcn_global_load_lds((glb_u32*)(src + v),
                                             (lds_u32*)&s_cls[v * 4], 16, 0, 0);
    }

    // ---- cls-independent work while staging is in flight
    if (tid < OO) {
        float4 g = gt_boxes[b * OO + tid];
        s_ax1[tid] = g.x; s_ay1[tid] = g.y; s_ax2[tid] = g.z; s_ay2[tid] = g.w;
        s_lab[tid] = gt_labels[b * OO + tid];
    }
    {
        unsigned long long k = partial[(size_t)b * (OO * CH) + tid];
        #pragma unroll
        for (int off = 8; off; off >>= 1) {
            unsigned long long v = __shfl_xor(k, off, 16);
            if (v > k) k = v;
        }
        if ((tid & 15) == 0) s_bdi[tid >> 4] = DD - 1 - (int)(k & 0xffffffffu);
    }
    const size_t gi = (size_t)b * DD + d;
    float best = 0.0f; int bi = 0;
    if (d < DD) { best = bovl[gi]; bi = (int)bidx[gi]; }

    __syncthreads();   // drains staging + LDS writes

    float sl1 = 0.0f, cepos = 0.0f; int npos = 0;
    if (d < DD) {
        #pragma unroll
        for (int o = 0; o < OO; ++o) {
            if (s_bdi[o] == d) { bi = o; best = 1.0f; }   // ascending o, last wins
        }
        int lab = (best < 0.5f) ? 0 : s_lab[bi];

        float v[CC];
        #pragma unroll
        for (int c = 0; c < CC; ++c) v[c] = s_cls[tid * CC + c];
        float m = v[0];
        #pragma unroll
        for (int c = 1; c < CC; ++c) m = fmaxf(m, v[c]);
        float s = 0.0f;
        #pragma unroll
        for (int c = 0; c < CC; ++c) s += __expf(v[c] - m);
        float xl = s_cls[tid * CC + lab];
        float ce = m + __logf(s) - xl;

        if (lab > 0) {
            npos = 1; cepos = ce;
            float ax1 = s_ax1[bi], ay1 = s_ay1[bi], ax2 = s_ax2[bi], ay2 = s_ay2[bi];
            float cx = (ax1 + ax2) * 0.5f, cy = (ay1 + ay2) * 0.5f;
            float w = ax2 - ax1, h = ay2 - ay1;
            float4 p = db[d];
            float gx = (cx - p.x) / (p.z / 10.0f);
            float gy = (cy - p.y) / (p.w / 10.0f);
            float gw = __logf(w / p.z) * 5.0f;
            float gh = __logf(h / p.w) * 5.0f;
            float4 lp = loc_pred[gi];
            sl1 = smoothl1(lp.x - gx) + smoothl1(lp.y - gy)
                + smoothl1(lp.z - gw) + smoothl1(lp.w - gh);
        }
        ce_neg[gi] = (lab > 0) ? 0.0f : ce;
    }

    #pragma unroll
    for (int off = 32; off; off >>= 1) {
        sl1   += __shfl_xor(sl1, off);
        cepos += __shfl_xor(cepos, off);
        npos  += __shfl_xor(npos, off);
    }
    const int w = tid >> 6;
    if ((tid & 63) == 0) { s_f[w*2+0] = sl1; s_f[w*2+1] = cepos; s_i[w] = npos; }
    __syncthreads();
    if (tid == 0) {
        float sv = 0, cp = 0; int np = 0;
        #pragma unroll
        for (int q = 0; q < 4; ++q) { sv += s_f[q*2+0]; cp += s_f[q*2+1]; np += s_i[q]; }
        const int pi = b * NBLK_D + jb;
        part_sl1[pi] = sv;
        part_ce[pi]  = cp;
        part_np[pi]  = np;
    }

    // ---- release: make this block's ce_neg + part_* device-visible, ticket
    __threadfence();                      // ALL threads: covers every lane's stores
    __syncthreads();
    if (tid == 0) {
        int prev = atomicAdd(&counters[b], 1);
        s_last = (prev == NBLK_D - 1) ? 1 : 0;
    }
    __syncthreads();
    if (!s_last) return;

    // ================= phase B: last arriver of image b ======================
    __threadfence();                      // acquire
    float isl1 = 0.0f, ice = 0.0f; int inp = 0;
    for (int jj = 0; jj < NBLK_D; ++jj) {   // uniform
        const int pi = b * NBLK_D + jj;
        isl1 += part_sl1[pi]; ice += part_ce[pi]; inp += part_np[pi];
    }
    int k0 = 3 * inp;
    if (k0 > DD) k0 = DD;

    float row = 0.0f;
    if (k0 > 0) {
        int* hist = (int*)s_cls;          // alias: s_cls dead in phase B
        unsigned kx[NV];
        #pragma unroll
        for (int q = 0; q < NV; ++q) {
            int dd = q * 256 + tid;
            float v = (dd < DD) ? ce_neg[(size_t)b * DD + dd] : 0.0f;
            unsigned u = __float_as_uint(v);
            kx[q] = u ^ ((unsigned)((int)u >> 31) | 0x80000000u);
        }
        unsigned prefix = 0u; int k = k0;
        #pragma unroll
        for (int p = 0; p < 4; ++p) {
            const int shift = 24 - 8 * p;
            hist[tid] = 0;
            __syncthreads();
            #pragma unroll
            for (int q = 0; q < NV; ++q) {
                if (p == 0 || ((kx[q] ^ prefix) >> (shift + 8)) == 0u)
                    atomicAdd(&hist[(kx[q] >> shift) & 255], 1);
            }
            __syncthreads();
            if (tid < 64) {   // wave 0: descending suffix scan, 4 bins/lane
                int h0 = hist[255 - 4*tid], h1 = hist[254 - 4*tid],
                    h2 = hist[253 - 4*tid], h3 = hist[252 - 4*tid];
                int sl = h0 + h1 + h2 + h3;
                int run = sl;
                #pragma unroll
                for (int off = 1; off < 64; off <<= 1) {
                    int v = __shfl_up(run, off);
                    if (tid >= off) run += v;
                }
                int pre = run - sl;
                if (pre < k && k <= pre + sl) {
                    int hh[4] = {h0, h1, h2, h3};
                    int c = pre, byte = -1, knew = 0;
                    #pragma unroll
                    for (int jx = 0; jx < 4; ++jx) {
                        if (byte < 0 && c + hh[jx] >= k) { byte = 255 - 4*tid - jx; knew = k - c; }
                        c += hh[jx];
                    }
                    s_pk[0] = prefix | ((unsigned)byte << shift);
                    s_pk[1] = (unsigned)knew;
                }
            }
            __syncthreads();
            prefix = s_pk[0]; k = (int)s_pk[1];
        }

        unsigned vb = (prefix & 0x80000000u) ? (prefix ^ 0x80000000u) : ~prefix;
        float vk = __uint_as_float(vb);

        float ssum = 0.0f; int cgt = 0;
        #pragma unroll
        for (int q = 0; q < NV; ++q) {
            if (kx[q] > prefix) {
                unsigned u = (kx[q] & 0x80000000u) ? (kx[q] ^ 0x80000000u) : ~kx[q];
                ssum += __uint_as_float(u);
                ++cgt;
            }
        }
        #pragma unroll
        for (int off = 32; off; off >>= 1) { ssum += __shfl_xor(ssum, off); cgt += __shfl_xor(cgt, off); }
        if ((tid & 63) == 0) { s_f[tid >> 6] = ssum; s_i[tid >> 6] = cgt; }
        __syncthreads();
        row = s_f[0]+s_f[1]+s_f[2]+s_f[3]
            + (float)(k0 - (s_i[0]+s_i[1]+s_i[2]+s_i[3])) * vk;
    }

    if (tid == 0) {
        img_sl1[b] = isl1; img_ce[b] = ice; img_np[b] = inp;
        conf_neg_part[b] = row;
    }
    __threadfence();
    __syncthreads();
    if (tid == 0) {
        int prev = atomicAdd(&counters[BB], 1);
        s_glast = (prev == BB - 1) ? 1 : 0;
    }
    __syncthreads();
    if (!s_glast) return;

    // ================= phase C: global finalize (one block) ==================
    __threadfence();
    float loc = 0.0f, cpos = 0.0f, cn = 0.0f; int npt = 0;
    for (int i = tid; i < BB; i += 256) {
        loc  += img_sl1[i];
        cpos += img_ce[i];
        npt  += img_np[i];
        cn   += conf_neg_part[i];
    }
    #pragma unroll
    for (int off = 32; off; off >>= 1) {
        loc  += __shfl_xor(loc, off);
        cpos += __shfl_xor(cpos, off);
        cn   += __shfl_xor(cn, off);
        npt  += __shfl_xor(npt, off);
    }
    if ((tid & 63) == 0) { s_f[w*3+0] = loc; s_f[w*3+1] = cpos; s_f[w*3+2] = cn; s_i[w] = npt; }
    __syncthreads();
    if (tid == 0) {
        float L = 0, P = 0, N = 0; int T = 0;
        #pragma unroll
        for (int q = 0; q < 4; ++q) { L += s_f[q*3]; P += s_f[q*3+1]; N += s_f[q*3+2]; T += s_i[q]; }
        float npf = (float)T;
        out[0] = L / (npf * 4.0f) + (N + P) / npf;
    }
}

extern "C" void kernel_launch(void* const* d_in, const int* in_sizes, int n_in,
                              void* d_out, int out_size, void* d_ws, size_t ws_size,
                              hipStream_t stream) {
    (void)in_sizes; (void)n_in; (void)out_size; (void)ws_size;
    const float4* loc_pred  = (const float4*)d_in[0];
    const float*  cls_pred  = (const float*)d_in[1];
    const float4* gt_boxes  = (const float4*)d_in[2];
    const int*    gt_labels = (const int*)d_in[3];
    const float4* db        = (const float4*)d_in[4];

    char* ws = (char*)d_ws;
    size_t off = 0;
    auto alloc = [&](size_t bytes) { char* p = ws + off; off = (off + bytes + 15) & ~(size_t)15; return p; };

    unsigned long long* partial = (unsigned long long*)alloc((size_t)BB * OO * CH * 8);
    float* ce_neg        = (float*)alloc((size_t)BB * DD * 4);
    float* bovl          = (float*)alloc((size_t)BB * DD * 4);
    unsigned char* bidx  = (unsigned char*)alloc((size_t)BB * DD);
    float* part_sl1      = (float*)alloc((size_t)NLB * 4);
    int*   part_np       = (int*)alloc((size_t)NLB * 4);
    float* part_ce       = (float*)alloc((size_t)NLB * 4);
    float* img_sl1       = (float*)alloc((size_t)BB * 4);
    float* img_ce        = (float*)alloc((size_t)BB * 4);
    int*   img_np        = (int*)alloc((size_t)BB * 4);
    float* conf_neg_part = (float*)alloc((size_t)BB * 4);
    int*   counters      = (int*)alloc((size_t)(BB + 1) * 4);

    match_a<<<dim3(CH, BB), 256, 0, stream>>>(gt_boxes, db, partial, bovl, bidx,
                                              counters);
    mega<<<dim3(NBLK_D, BB), 256, 0, stream>>>(loc_pred, cls_pred, gt_boxes,
                                               gt_labels, db, partial, bovl, bidx,
                                               ce_neg, part_sl1, part_np, part_ce,
                                               img_sl1, img_ce, img_np, conf_neg_part,
                                               counters, (float*)d_out);
}

// Round 11
// 67.194 us; speedup vs baseline: 8.2484x; 8.2484x over previous
//
#include <hip/hip_runtime.h>

#define BB 128
#define DD 8732
#define OO 16
#define CC 21
#define CH 16        // chunks per image in match phase A
#define CHUNK 546    // ceil(DD/CH)
#define NBLK_D 35    // ceil(DD/256)
#define NLB (BB * NBLK_D)
#define NV 35        // per-thread register values in topk

typedef __attribute__((address_space(3))) unsigned int lds_u32;
typedef const __attribute__((address_space(1))) unsigned int glb_u32;

__device__ __forceinline__ float smoothl1(float d) {
    float ad = fabsf(d);
    return (ad < 1.0f) ? 0.5f * d * d : ad - 0.5f;
}

// ---- Phase A: per-chunk argmax_d(iou) per gt o  +  per-d packed best ------
// key = (iou_bits << 32) | (DD-1-d)  -> u64 max == max iou, tie -> smallest d
__global__ __launch_bounds__(256) void match_a(
    const float4* __restrict__ gt_boxes,   // [B*O] xyxy
    const float4* __restrict__ db,         // [D] cxcywh
    unsigned long long* __restrict__ partial, // [B][O][CH]
    unsigned* __restrict__ bpk,            // [B*D] (iou_bits&0xFFFFFF00)|argmax_o
    int* __restrict__ done_counter)        // zeroed here for topk_final
{
    const int b = blockIdx.y, ch = blockIdx.x, tid = threadIdx.x;
    if (b == 0 && ch == 0 && tid == 0) *done_counter = 0;

    __shared__ float s_ax1[OO], s_ay1[OO], s_ax2[OO], s_ay2[OO], s_area[OO];
    __shared__ unsigned long long s_keys[OO][257];   // padded stride

    if (tid < OO) {
        float4 g = gt_boxes[b * OO + tid];
        s_ax1[tid] = g.x; s_ay1[tid] = g.y; s_ax2[tid] = g.z; s_ay2[tid] = g.w;
        s_area[tid] = (g.z - g.x) * (g.w - g.y);
    }
    __syncthreads();

    unsigned long long key[OO];
    #pragma unroll
    for (int o = 0; o < OO; ++o) key[o] = 0ull;

    const int d0 = ch * CHUNK;
    const int dend = min(d0 + CHUNK, DD);
    for (int d = d0 + tid; d < dend; d += 256) {
        float4 p = db[d];
        float px1 = p.x - p.z * 0.5f, py1 = p.y - p.w * 0.5f;
        float px2 = p.x + p.z * 0.5f, py2 = p.y + p.w * 0.5f;
        float area_b = (px2 - px1) * (py2 - py1);
        unsigned dl = (unsigned)(DD - 1 - d);
        float best = -1.0f; int bi = 0;
        #pragma unroll
        for (int o = 0; o < OO; ++o) {
            float w = fmaxf(fminf(s_ax2[o], px2) - fmaxf(s_ax1[o], px1), 0.0f);
            float h = fmaxf(fminf(s_ay2[o], py2) - fmaxf(s_ay1[o], py1), 0.0f);
            float inter = w * h;
            float uni = s_area[o] + area_b - inter;
            float iou = inter * __builtin_amdgcn_rcpf(uni);   // v_rcp_f32
            unsigned long long kk = ((unsigned long long)__float_as_uint(iou) << 32) | dl;
            if (kk > key[o]) key[o] = kk;
            if (iou > best) { best = iou; bi = o; }   // first occurrence over o
        }
        bpk[(size_t)b * DD + d] = (__float_as_uint(best) & 0xFFFFFF00u) | (unsigned)bi;
    }
    #pragma unroll
    for (int o = 0; o < OO; ++o) s_keys[o][tid] = key[o];
    __syncthreads();

    const int o = tid >> 4, j = tid & 15;
    unsigned long long mx = s_keys[o][j];
    #pragma unroll
    for (int m = 1; m < 16; ++m) {
        unsigned long long v = s_keys[o][j + 16 * m];
        if (v > mx) mx = v;
    }
    #pragma unroll
    for (int off = 8; off; off >>= 1) {
        unsigned long long v = __shfl_xor(mx, off, 16);
        if (v > mx) mx = v;
    }
    if (j == 0) partial[((size_t)b * OO + o) * CH + ch] = mx;
}

// ---- fused: async LDS staging + bdi-reduce + override table + SL1 + CE ----
__global__ __launch_bounds__(256) void fused_main(
    const float4* __restrict__ loc_pred,   // [B*D]
    const float*  __restrict__ cls,        // [B*D*C]
    const float4* __restrict__ gt_boxes,   // [B*O]
    const int*    __restrict__ gt_labels,  // [B*O]
    const float4* __restrict__ db,         // [D]
    const unsigned long long* __restrict__ partial, // [B][O][CH]
    const unsigned* __restrict__ bpk,      // [B*D]
    float* __restrict__ ce_neg,            // [B*D]
    float* __restrict__ part_sl1,          // [NLB] layout [b][jb]
    int*   __restrict__ part_np,           // [NLB]
    float* __restrict__ part_ce)           // [NLB]
{
    const int b = blockIdx.y, jb = blockIdx.x, tid = threadIdx.x;
    const int d = jb * 256 + tid;
    __shared__ float s_cls[256 * CC];      // 21504 B
    __shared__ float s_ax1[OO], s_ay1[OO], s_ax2[OO], s_ay2[OO];
    __shared__ int   s_lab[OO], s_bdi[OO];
    __shared__ unsigned char s_ovr[256];
    __shared__ float s_f[8];
    __shared__ int   s_i[4];

    // ---- issue async global->LDS staging FIRST (16B/lane/issue, linear dest)
    const int nrow = min(256, DD - jb * 256);
    const int nvec = nrow * CC / 4;        // 1344 full, 147 tail
    const float4* src = (const float4*)(cls + ((size_t)b * DD + (size_t)jb * 256) * CC);
    if (nvec == 1344) {
        #pragma unroll
        for (int c = 0; c < 5; ++c) {
            int v = c * 256 + tid;
            __builtin_amdgcn_global_load_lds((glb_u32*)(src + v),
                                             (lds_u32*)&s_cls[v * 4], 16, 0, 0);
        }
        if (tid < 64) {
            int v = 5 * 256 + tid;
            __builtin_amdgcn_global_load_lds((glb_u32*)(src + v),
                                             (lds_u32*)&s_cls[v * 4], 16, 0, 0);
        }
    } else {
        for (int v = tid; v < nvec; v += 256)
            __builtin_amdgcn_global_load_lds((glb_u32*)(src + v),
                                             (lds_u32*)&s_cls[v * 4], 16, 0, 0);
    }

    // ---- cls-independent work while staging is in flight
    s_ovr[tid] = 0xFF;
    if (tid < OO) {
        float4 g = gt_boxes[b * OO + tid];
        s_ax1[tid] = g.x; s_ay1[tid] = g.y; s_ax2[tid] = g.z; s_ay2[tid] = g.w;
        s_lab[tid] = gt_labels[b * OO + tid];
    }
    {   // in-block match_b: 16x16 chunk partials -> s_bdi
        unsigned long long k = partial[(size_t)b * (OO * CH) + tid]; // o=tid>>4, ch=tid&15
        #pragma unroll
        for (int off = 8; off; off >>= 1) {
            unsigned long long v = __shfl_xor(k, off, 16);
            if (v > k) k = v;
        }
        if ((tid & 15) == 0) s_bdi[tid >> 4] = DD - 1 - (int)(k & 0xffffffffu);
    }
    const size_t gi = (size_t)b * DD + d;
    unsigned upk = 0u;
    if (d < DD) upk = bpk[gi];             // in flight across barrier

    __syncthreads();   // drains staging + LDS writes; s_bdi/s_ovr-init visible

    if (tid == 0) {    // serial scatter: ascending o, last write wins (XLA)
        #pragma unroll
        for (int o = 0; o < OO; ++o) {
            int ds = s_bdi[o] - jb * 256;
            if (0 <= ds && ds < 256) s_ovr[ds] = (unsigned char)o;
        }
    }
    __syncthreads();

    float sl1 = 0.0f, cepos = 0.0f; int npos = 0;
    if (d < DD) {
        int bi = (int)(upk & 0xFFu);
        float best = __uint_as_float(upk & 0xFFFFFF00u);
        int ov = s_ovr[tid];
        if (ov != 0xFF) { bi = ov; best = 1.0f; }
        int lab = (best < 0.5f) ? 0 : s_lab[bi];

        // CE from LDS row (word stride 21, coprime with 32 banks -> conflict-free)
        float v[CC];
        #pragma unroll
        for (int c = 0; c < CC; ++c) v[c] = s_cls[tid * CC + c];
        float m = v[0];
        #pragma unroll
        for (int c = 1; c < CC; ++c) m = fmaxf(m, v[c]);
        float s = 0.0f;
        #pragma unroll
        for (int c = 0; c < CC; ++c) s += __expf(v[c] - m);   // v_exp_f32
        float xl = s_cls[tid * CC + lab];                     // one runtime-offset read
        float ce = m + __logf(s) - xl;                        // v_log_f32

        if (lab > 0) {
            npos = 1; cepos = ce;
            float ax1 = s_ax1[bi], ay1 = s_ay1[bi], ax2 = s_ax2[bi], ay2 = s_ay2[bi];
            float cx = (ax1 + ax2) * 0.5f, cy = (ay1 + ay2) * 0.5f;
            float w = ax2 - ax1, h = ay2 - ay1;
            float4 p = db[d];
            float gx = (cx - p.x) / (p.z / 10.0f);
            float gy = (cy - p.y) / (p.w / 10.0f);
            float gw = __logf(w / p.z) * 5.0f;
            float gh = __logf(h / p.w) * 5.0f;
            float4 lp = loc_pred[gi];
            sl1 = smoothl1(lp.x - gx) + smoothl1(lp.y - gy)
                + smoothl1(lp.z - gw) + smoothl1(lp.w - gh);
        }
        ce_neg[gi] = (lab > 0) ? 0.0f : ce;
    }

    #pragma unroll
    for (int off = 32; off; off >>= 1) {
        sl1   += __shfl_xor(sl1, off);
        cepos += __shfl_xor(cepos, off);
        npos  += __shfl_xor(npos, off);
    }
    const int w = tid >> 6;
    if ((tid & 63) == 0) { s_f[w*2+0] = sl1; s_f[w*2+1] = cepos; s_i[w] = npos; }
    __syncthreads();
    if (tid == 0) {
        float sv = 0, cp = 0; int np = 0;
        #pragma unroll
        for (int q = 0; q < 4; ++q) { sv += s_f[q*2+0]; cp += s_f[q*2+1]; np += s_i[q]; }
        const int pi = b * NBLK_D + jb;
        part_sl1[pi] = sv;
        part_ce[pi]  = cp;
        part_np[pi]  = np;
    }
}

// ---- topk via 4-pass radix select + last-block finalize -------------------
// order-preserving key: k = u ^ (u<0 ? 0xFFFFFFFF : 0x80000000); larger f -> larger k
__global__ __launch_bounds__(256) void topk_final(
    const float* __restrict__ ce_neg,
    const int*   __restrict__ part_np,        // [B][NBLK_D]
    const float* __restrict__ part_sl1,       // [NLB]
    const float* __restrict__ part_ce,        // [NLB]
    float* __restrict__ conf_neg_part,        // [B]
    int*   __restrict__ done_counter,
    float* __restrict__ out)
{
    const int b = blockIdx.x, tid = threadIdx.x;
    __shared__ int      hist[256];
    __shared__ unsigned s_pk[2];
    __shared__ float    s_f[12];
    __shared__ int      s_c[4];
    __shared__ int      s_last;

    int np = 0;
    #pragma unroll
    for (int jb = 0; jb < NBLK_D; ++jb) np += part_np[b * NBLK_D + jb];  // uniform
    int k0 = 3 * np;
    if (k0 > DD) k0 = DD;

    float row = 0.0f;
    if (k0 > 0) {    // uniform per block
        unsigned kx[NV];
        #pragma unroll
        for (int q = 0; q < NV; ++q) {
            int d = q * 256 + tid;
            float v = (d < DD) ? ce_neg[(size_t)b * DD + d] : 0.0f;  // pads harmless
            unsigned u = __float_as_uint(v);
            kx[q] = u ^ ((unsigned)((int)u >> 31) | 0x80000000u);
        }

        unsigned prefix = 0u; int k = k0;
        #pragma unroll
        for (int p = 0; p < 4; ++p) {
            const int shift = 24 - 8 * p;
            hist[tid] = 0;
            __syncthreads();
            #pragma unroll
            for (int q = 0; q < NV; ++q) {
                if (p == 0 || ((kx[q] ^ prefix) >> (shift + 8)) == 0u)
                    atomicAdd(&hist[(kx[q] >> shift) & 255], 1);
            }
            __syncthreads();
            if (tid < 64) {   // wave 0: descending suffix scan, 4 bins/lane
                int h0 = hist[255 - 4*tid], h1 = hist[254 - 4*tid],
                    h2 = hist[253 - 4*tid], h3 = hist[252 - 4*tid];
                int sl = h0 + h1 + h2 + h3;
                int run = sl;
                #pragma unroll
                for (int off = 1; off < 64; off <<= 1) {
                    int v = __shfl_up(run, off);
                    if (tid >= off) run += v;
                }
                int pre = run - sl;           // count in bins strictly higher
                if (pre < k && k <= pre + sl) {   // exactly one lane
                    int hh[4] = {h0, h1, h2, h3};
                    int c = pre, byte = -1, knew = 0;
                    #pragma unroll
                    for (int j = 0; j < 4; ++j) {
                        if (byte < 0 && c + hh[j] >= k) { byte = 255 - 4*tid - j; knew = k - c; }
                        c += hh[j];
                    }
                    s_pk[0] = prefix | ((unsigned)byte << shift);
                    s_pk[1] = (unsigned)knew;
                }
            }
            __syncthreads();
            prefix = s_pk[0]; k = (int)s_pk[1];
        }

        unsigned vb = (prefix & 0x80000000u) ? (prefix ^ 0x80000000u) : ~prefix;
        float vk = __uint_as_float(vb);        // exact k-th largest value

        float ssum = 0.0f; int cgt = 0;
        #pragma unroll
        for (int q = 0; q < NV; ++q) {
            if (kx[q] > prefix) {
                unsigned u = (kx[q] & 0x80000000u) ? (kx[q] ^ 0x80000000u) : ~kx[q];
                ssum += __uint_as_float(u);
                ++cgt;
            }
        }
        #pragma unroll
        for (int off = 32; off; off >>= 1) { ssum += __shfl_xor(ssum, off); cgt += __shfl_xor(cgt, off); }
        if ((tid & 63) == 0) { s_f[tid >> 6] = ssum; s_c[tid >> 6] = cgt; }
        __syncthreads();
        row = s_f[0]+s_f[1]+s_f[2]+s_f[3]
            + (float)(k0 - (s_c[0]+s_c[1]+s_c[2]+s_c[3])) * vk;   // exact tie handling
    }

    if (tid == 0) {
        conf_neg_part[b] = row;
        __threadfence();
        int prev = atomicAdd(done_counter, 1);
        s_last = (prev == BB - 1) ? 1 : 0;
    }
    __syncthreads();
    if (s_last) {                                // one block; fixed-order reduce
        __threadfence();
        float loc = 0.0f, cp = 0.0f; int npt = 0;
        for (int i = tid; i < NLB; i += 256) {
            loc += part_sl1[i]; cp += part_ce[i]; npt += part_np[i];
        }
        float cn = (tid < BB) ? conf_neg_part[tid] : 0.0f;
        #pragma unroll
        for (int off = 32; off; off >>= 1) {
            loc += __shfl_xor(loc, off);
            cp  += __shfl_xor(cp, off);
            cn  += __shfl_xor(cn, off);
            npt += __shfl_xor(npt, off);
        }
        const int w = tid >> 6;
        if ((tid & 63) == 0) { s_f[w*3+0] = loc; s_f[w*3+1] = cp; s_f[w*3+2] = cn; s_c[w] = npt; }
        __syncthreads();
        if (tid == 0) {
            float L = 0, P = 0, N = 0; int T = 0;
            #pragma unroll
            for (int q = 0; q < 4; ++q) { L += s_f[q*3]; P += s_f[q*3+1]; N += s_f[q*3+2]; T += s_c[q]; }
            float npf = (float)T;
            out[0] = L / (npf * 4.0f) + (N + P) / npf;
        }
    }
}

extern "C" void kernel_launch(void* const* d_in, const int* in_sizes, int n_in,
                              void* d_out, int out_size, void* d_ws, size_t ws_size,
                              hipStream_t stream) {
    (void)in_sizes; (void)n_in; (void)out_size; (void)ws_size;
    const float4* loc_pred  = (const float4*)d_in[0];
    const float*  cls_pred  = (const float*)d_in[1];
    const float4* gt_boxes  = (const float4*)d_in[2];
    const int*    gt_labels = (const int*)d_in[3];
    const float4* db        = (const float4*)d_in[4];

    char* ws = (char*)d_ws;
    size_t off = 0;
    auto alloc = [&](size_t bytes) { char* p = ws + off; off = (off + bytes + 15) & ~(size_t)15; return p; };

    unsigned long long* partial = (unsigned long long*)alloc((size_t)BB * OO * CH * 8);
    float* ce_neg        = (float*)alloc((size_t)BB * DD * 4);
    unsigned* bpk        = (unsigned*)alloc((size_t)BB * DD * 4);
    float* part_sl1      = (float*)alloc((size_t)NLB * 4);
    int*   part_np       = (int*)alloc((size_t)NLB * 4);
    float* part_ce       = (float*)alloc((size_t)NLB * 4);
    float* conf_neg_part = (float*)alloc((size_t)BB * 4);
    int*   done_counter  = (int*)alloc(sizeof(int));

    match_a<<<dim3(CH, BB), 256, 0, stream>>>(gt_boxes, db, partial, bpk,
                                              done_counter);
    fused_main<<<dim3(NBLK_D, BB), 256, 0, stream>>>(loc_pred, cls_pred, gt_boxes,
                                                     gt_labels, db, partial, bpk,
                                                     ce_neg, part_sl1, part_np, part_ce);
    topk_final<<<BB, 256, 0, stream>>>(ce_neg, part_np, part_sl1, part_ce,
                                       conf_neg_part, done_counter, (float*)d_out);
}